// Round 1
// baseline (541.893 us; speedup 1.0000x reference)
//
#include <hip/hip_runtime.h>
#include <hip/hip_bf16.h>

// ---------------- problem dims ----------------
#define BATCH 64
#define IH 250
#define IW 250
#define C1O 6
#define OH1 124
#define OW1 124
#define PH1 123
#define PW1 123
#define C2O 15
#define OH2 62
#define OW2 62
#define PH2 61
#define PW2 61
#define KFC 55815          // 15*61*61
#define KPAD 55816         // padded row stride (16B-aligned rows)
#define NFC1 120
#define KC 248             // K-chunk for fc1 split-K
#define NCH 226            // ceil(55815/248)
#define SA_STRIDE 252      // LDS row stride (floats), %4==0, %32!=0

// workspace offsets (floats)
#define oW   ((size_t)0)                     // 120*55816 = 6697920
#define oC1  ((size_t)6697920)               // conv1 out 5904384 (reused for conv2 out)
#define oP1  ((size_t)12602304)              // pool1 out 5809536
#define oA   ((size_t)18411840)              // padded flat features 64*55816 = 3572224
#define oPart ((size_t)21984064)             // 226*120*64 = 1735680
#define oFC1 ((size_t)23719744)              // 64*120

// ---------------- kernels ----------------

__global__ __launch_bounds__(256) void wpad_k(const float* __restrict__ w, float* __restrict__ wp) {
    int col = blockIdx.x * 256 + threadIdx.x;
    int row = blockIdx.y;
    if (col < KPAD)
        wp[(size_t)row * KPAD + col] = (col < KFC) ? w[(size_t)row * KFC + col] : 0.f;
}

__global__ __launch_bounds__(256) void conv1_k(const float* __restrict__ x, const float* __restrict__ w,
                                               const float* __restrict__ bias, float* __restrict__ out) {
    int idx = blockIdx.x * 256 + threadIdx.x;
    if (idx >= BATCH * C1O * OH1 * OW1) return;
    int ox = idx % OW1;
    int t = idx / OW1;
    int oy = t % OH1; t /= OH1;
    int c = t % C1O;
    int b = t / C1O;
    float acc = bias[c];
    int iy0 = 2 * oy - 1, ix0 = 2 * ox - 1;
    for (int ic = 0; ic < 3; ++ic) {
        const float* xp = x + ((size_t)(b * 3 + ic)) * IH * IW;
        const float* wp = w + (c * 3 + ic) * 25;
        #pragma unroll
        for (int ky = 0; ky < 5; ++ky) {
            int iy = iy0 + ky;
            if (iy < 0) continue;              // upper bound never exceeded (max 249)
            #pragma unroll
            for (int kx = 0; kx < 5; ++kx) {
                int ix = ix0 + kx;
                if (ix < 0) continue;
                acc = fmaf(xp[iy * IW + ix], wp[ky * 5 + kx], acc);
            }
        }
    }
    out[idx] = fmaxf(acc, 0.f);
}

__global__ __launch_bounds__(256) void pool1_k(const float* __restrict__ in, float* __restrict__ out) {
    int idx = blockIdx.x * 256 + threadIdx.x;
    if (idx >= BATCH * C1O * PH1 * PW1) return;
    int x = idx % PW1;
    int t = idx / PW1;
    int y = t % PH1;
    int bc = t / PH1;
    const float* p = in + ((size_t)bc * OH1 + y) * OW1 + x;
    float m = fmaxf(fmaxf(p[0], p[1]), fmaxf(p[OW1], p[OW1 + 1]));
    out[idx] = m;
}

__global__ __launch_bounds__(256) void conv2_k(const float* __restrict__ in, const float* __restrict__ w,
                                               const float* __restrict__ bias, float* __restrict__ out) {
    int idx = blockIdx.x * 256 + threadIdx.x;
    if (idx >= BATCH * C2O * OH2 * OW2) return;
    int ox = idx % OW2;
    int t = idx / OW2;
    int oy = t % OH2; t /= OH2;
    int c = t % C2O;
    int b = t / C2O;
    float acc = bias[c];
    int iy0 = 2 * oy - 1, ix0 = 2 * ox - 1;
    for (int ic = 0; ic < 6; ++ic) {
        const float* xp = in + ((size_t)(b * 6 + ic)) * PH1 * PW1;
        const float* wp = w + (c * 6 + ic) * 9;
        #pragma unroll
        for (int ky = 0; ky < 3; ++ky) {
            int iy = iy0 + ky;
            if (iy < 0 || iy >= PH1) continue;
            #pragma unroll
            for (int kx = 0; kx < 3; ++kx) {
                int ix = ix0 + kx;
                if (ix < 0 || ix >= PW1) continue;
                acc = fmaf(xp[iy * PW1 + ix], wp[ky * 3 + kx], acc);
            }
        }
    }
    out[idx] = fmaxf(acc, 0.f);
}

// pool2 writes the flattened, relu'd, padded feature matrix A[64][55816]
__global__ __launch_bounds__(256) void pool2_k(const float* __restrict__ in, float* __restrict__ A) {
    int idx = blockIdx.x * 256 + threadIdx.x;   // covers 64*55816 exactly
    int col = idx % KPAD;
    int b = idx / KPAD;
    if (col >= KFC) { A[(size_t)b * KPAD + col] = 0.f; return; }
    int c = col / (PH2 * PW2);
    int r = col % (PH2 * PW2);
    int y = r / PW2;
    int x = r % PW2;
    const float* p = in + (((size_t)(b * C2O + c)) * OH2 + y) * OW2 + x;
    float m = fmaxf(fmaxf(p[0], p[1]), fmaxf(p[OW2], p[OW2 + 1]));
    A[(size_t)b * KPAD + col] = m;
}

// fc1 split-K stage 1: block = one K-chunk; A tile in LDS; 4 waves x 6 outputs x 5 passes
__global__ __launch_bounds__(256) void fc1_stage1(const float* __restrict__ A, const float* __restrict__ Wp,
                                                  float* __restrict__ part) {
    __shared__ float sA[64 * SA_STRIDE];
    const int chunk = blockIdx.x;
    const int k0 = chunk * KC;
    const int tid = threadIdx.x;

    // load A tile [64][248] as float4s
    for (int f = tid; f < 64 * 62; f += 256) {
        int row = f / 62;
        int c4 = f - row * 62;
        int k = k0 + 4 * c4;
        float4 v;
        if (k + 3 < KFC) {
            v = *(const float4*)(A + (size_t)row * KPAD + k);
        } else {
            v.x = (k + 0 < KFC) ? A[(size_t)row * KPAD + k + 0] : 0.f;
            v.y = (k + 1 < KFC) ? A[(size_t)row * KPAD + k + 1] : 0.f;
            v.z = (k + 2 < KFC) ? A[(size_t)row * KPAD + k + 2] : 0.f;
            v.w = (k + 3 < KFC) ? A[(size_t)row * KPAD + k + 3] : 0.f;
        }
        *(float4*)(sA + row * SA_STRIDE + 4 * c4) = v;
    }
    __syncthreads();

    const int lane = tid & 63;
    const int wv = tid >> 6;
    const float* sArow = sA + lane * SA_STRIDE;

    for (int p = 0; p < 5; ++p) {
        int o0 = __builtin_amdgcn_readfirstlane(p * 24 + wv * 6);
        float acc0 = 0.f, acc1 = 0.f, acc2 = 0.f, acc3 = 0.f, acc4 = 0.f, acc5 = 0.f;
        const float* w0 = Wp + (size_t)o0 * KPAD + k0;
        for (int k4 = 0; k4 < 62; ++k4) {
            float4 a = *(const float4*)(sArow + 4 * k4);
            float4 w;
            w = *(const float4*)(w0 + 0 * (size_t)KPAD + 4 * k4);
            acc0 = fmaf(a.x, w.x, fmaf(a.y, w.y, fmaf(a.z, w.z, fmaf(a.w, w.w, acc0))));
            w = *(const float4*)(w0 + 1 * (size_t)KPAD + 4 * k4);
            acc1 = fmaf(a.x, w.x, fmaf(a.y, w.y, fmaf(a.z, w.z, fmaf(a.w, w.w, acc1))));
            w = *(const float4*)(w0 + 2 * (size_t)KPAD + 4 * k4);
            acc2 = fmaf(a.x, w.x, fmaf(a.y, w.y, fmaf(a.z, w.z, fmaf(a.w, w.w, acc2))));
            w = *(const float4*)(w0 + 3 * (size_t)KPAD + 4 * k4);
            acc3 = fmaf(a.x, w.x, fmaf(a.y, w.y, fmaf(a.z, w.z, fmaf(a.w, w.w, acc3))));
            w = *(const float4*)(w0 + 4 * (size_t)KPAD + 4 * k4);
            acc4 = fmaf(a.x, w.x, fmaf(a.y, w.y, fmaf(a.z, w.z, fmaf(a.w, w.w, acc4))));
            w = *(const float4*)(w0 + 5 * (size_t)KPAD + 4 * k4);
            acc5 = fmaf(a.x, w.x, fmaf(a.y, w.y, fmaf(a.z, w.z, fmaf(a.w, w.w, acc5))));
        }
        size_t base = ((size_t)chunk * NFC1 + o0) * 64 + lane;
        part[base + 0 * 64] = acc0;
        part[base + 1 * 64] = acc1;
        part[base + 2 * 64] = acc2;
        part[base + 3 * 64] = acc3;
        part[base + 4 * 64] = acc4;
        part[base + 5 * 64] = acc5;
    }
}

__global__ __launch_bounds__(256) void fc1_stage2(const float* __restrict__ part, const float* __restrict__ bias,
                                                  float* __restrict__ out) {
    int idx = blockIdx.x * 256 + threadIdx.x;   // 7680 total
    int o = idx >> 6;
    int b = idx & 63;
    float s = 0.f;
    for (int c = 0; c < NCH; ++c) s += part[(size_t)c * (NFC1 * 64) + idx];
    out[b * NFC1 + o] = fmaxf(s + bias[o], 0.f);
}

// tail: fc2(rows 0..3) + fidelity kernel + 3 dense layers + softmax. one wave per batch row.
__global__ __launch_bounds__(64) void tail_k(const float* __restrict__ fc1o,
                                             const float* __restrict__ fc2w, const float* __restrict__ fc2b,
                                             const float* __restrict__ centers,
                                             const float* __restrict__ w1, const float* __restrict__ b1,
                                             const float* __restrict__ w2, const float* __restrict__ b2,
                                             const float* __restrict__ w3, const float* __restrict__ b3,
                                             float* __restrict__ out) {
    int b = blockIdx.x;
    int lane = threadIdx.x;
    __shared__ float h[120];
    __shared__ float feat[4];
    __shared__ float bufA[64];
    __shared__ float bufB[64];

    for (int i = lane; i < NFC1; i += 64) h[i] = fc1o[b * NFC1 + i];
    __syncthreads();

    // fc2 rows 0..3 (only the first 4 features are ever used)
    int j = lane >> 4, p = lane & 15;
    float s = 0.f;
    for (int o = p; o < NFC1; o += 16) s = fmaf(fc2w[j * NFC1 + o], h[o], s);
    #pragma unroll
    for (int off = 8; off; off >>= 1) s += __shfl_xor(s, off, 16);
    if (p == 0) feat[j] = fmaxf(s + fc2b[j], 0.f);
    __syncthreads();

    // fidelity kernel vs 64 centers
    float prod = 1.f;
    #pragma unroll
    for (int i = 0; i < 4; ++i) prod *= cosf(0.5f * (feat[i] - centers[lane * 84 + i]));
    bufA[lane] = fabsf(prod);
    __syncthreads();

    float s1 = b1[lane];
    for (int jj = 0; jj < 64; ++jj) s1 = fmaf(w1[lane * 64 + jj], bufA[jj], s1);
    bufB[lane] = fmaxf(s1, 0.f);
    __syncthreads();

    float s2 = b2[lane];
    for (int jj = 0; jj < 64; ++jj) s2 = fmaf(w2[lane * 64 + jj], bufB[jj], s2);
    bufA[lane] = fmaxf(s2, 0.f);
    __syncthreads();

    if (lane < 2) {
        float s3 = b3[lane];
        for (int jj = 0; jj < 64; ++jj) s3 = fmaf(w3[lane * 64 + jj], bufA[jj], s3);
        float other = __shfl_xor(s3, 1, 2);
        float m = fmaxf(s3, other);
        float e = expf(s3 - m), eo = expf(other - m);
        out[b * 2 + lane] = e / (e + eo);
    }
}

// ---------------- launcher ----------------
extern "C" void kernel_launch(void* const* d_in, const int* in_sizes, int n_in,
                              void* d_out, int out_size, void* d_ws, size_t ws_size,
                              hipStream_t stream) {
    const float* x       = (const float*)d_in[0];
    const float* conv1_w = (const float*)d_in[1];
    const float* conv1_b = (const float*)d_in[2];
    const float* conv2_w = (const float*)d_in[3];
    const float* conv2_b = (const float*)d_in[4];
    const float* fc1_w   = (const float*)d_in[5];
    const float* fc1_b   = (const float*)d_in[6];
    const float* fc2_w   = (const float*)d_in[7];
    const float* fc2_b   = (const float*)d_in[8];
    const float* centers = (const float*)d_in[9];
    const float* cls_w1  = (const float*)d_in[10];
    const float* cls_b1  = (const float*)d_in[11];
    const float* cls_w2  = (const float*)d_in[12];
    const float* cls_b2  = (const float*)d_in[13];
    const float* cls_w3  = (const float*)d_in[14];
    const float* cls_b3  = (const float*)d_in[15];
    float* ws = (float*)d_ws;
    float* outp = (float*)d_out;

    float* Wp    = ws + oW;
    float* c1out = ws + oC1;   // reused as conv2 out
    float* p1out = ws + oP1;
    float* Abuf  = ws + oA;
    float* partb = ws + oPart;
    float* fc1o  = ws + oFC1;

    // pad-copy fc1 weights (independent of conv chain)
    {
        dim3 g((KPAD + 255) / 256, NFC1);
        hipLaunchKernelGGL(wpad_k, g, dim3(256), 0, stream, fc1_w, Wp);
    }
    // conv1 + relu
    {
        int total = BATCH * C1O * OH1 * OW1;
        hipLaunchKernelGGL(conv1_k, dim3(total / 256), dim3(256), 0, stream, x, conv1_w, conv1_b, c1out);
    }
    // pool1
    {
        int total = BATCH * C1O * PH1 * PW1;
        hipLaunchKernelGGL(pool1_k, dim3((total + 255) / 256), dim3(256), 0, stream, c1out, p1out);
    }
    // conv2 + relu (writes into c1out region — conv1 output dead after pool1)
    {
        int total = BATCH * C2O * OH2 * OW2;
        hipLaunchKernelGGL(conv2_k, dim3(total / 256), dim3(256), 0, stream, p1out, conv2_w, conv2_b, c1out);
    }
    // pool2 -> padded A
    {
        int total = BATCH * KPAD;
        hipLaunchKernelGGL(pool2_k, dim3(total / 256), dim3(256), 0, stream, c1out, Abuf);
    }
    // fc1 split-K
    hipLaunchKernelGGL(fc1_stage1, dim3(NCH), dim3(256), 0, stream, Abuf, Wp, partb);
    hipLaunchKernelGGL(fc1_stage2, dim3(7680 / 256), dim3(256), 0, stream, partb, fc1_b, fc1o);
    // tail
    hipLaunchKernelGGL(tail_k, dim3(BATCH), dim3(64), 0, stream,
                       fc1o, fc2_w, fc2_b, centers, cls_w1, cls_b1, cls_w2, cls_b2, cls_w3, cls_b3, outp);
}

// Round 2
// 249.388 us; speedup vs baseline: 2.1729x; 2.1729x over previous
//
#include <hip/hip_runtime.h>
#include <hip/hip_bf16.h>

// ---------------- problem dims ----------------
#define BATCH 64
#define C1 6
#define IH 250
#define IW 250
#define P1H 123
#define P1W 123
#define C2 15
#define P2H 61
#define P2W 61
#define KFC 55815          // 15*61*61
#define KPAD 55816         // padded feature row stride
#define NFC1 120
#define KC 248
#define NCH 226            // ceil(55815/248)

// workspace offsets (floats)
#define oP1   ((size_t)0)                       // 64*6*123*123 = 5809536
#define oA    ((size_t)5809536)                 // 64*55816     = 3572224
#define oPART ((size_t)(5809536+3572224))       // 226*120*64   = 1735680
#define oFC1  ((size_t)(5809536+3572224+1735680)) // 7680

// ============ conv1 (3->6, k5, s2, p1) + ReLU + MaxPool2s1, fused ============
// grid: 512 = 64 b * 8 row-groups ; block 256
// thread: g = tid>>7 (3-ch group, wave-uniform), t = (tid>>5)&3 (row tile), s = tid&31 (col strip, 31 used)
__global__ __launch_bounds__(256) void conv1_pool(const float* __restrict__ x,
        const float* __restrict__ w, const float* __restrict__ bias,
        float* __restrict__ out) {
    __shared__ float plane[37 * 252];
    const int tid = threadIdx.x;
    const int b  = blockIdx.x >> 3;
    const int G  = blockIdx.x & 7;
    const int p0 = G * 16;                     // first pool row of block
    const int g  = __builtin_amdgcn_readfirstlane(tid >> 7);
    const int t  = (tid >> 5) & 3;
    const int s  = tid & 31;

    float acc[5][4][3];
    #pragma unroll
    for (int c3 = 0; c3 < 3; ++c3) {
        const float bz = bias[g * 3 + c3];     // uniform -> s_load
        #pragma unroll
        for (int r = 0; r < 5; ++r)
            #pragma unroll
            for (int j = 0; j < 4; ++j)
                acc[r][j][c3] = bz;
    }

    for (int ic = 0; ic < 3; ++ic) {
        __syncthreads();
        // stage rows iy = 2*p0-1+row (row 0..36), cols ix = col-1 (col 0..251)
        const float* xp = x + (size_t)(b * 3 + ic) * (IH * IW);
        for (int i = tid; i < 37 * 63; i += 256) {
            const int row = i / 63;
            const int c4  = i - row * 63;
            const int iy  = 2 * p0 - 1 + row;
            float4 v;
            float* vv = (float*)&v;
            #pragma unroll
            for (int e = 0; e < 4; ++e) {
                const int ix = 4 * c4 + e - 1;
                vv[e] = (iy >= 0 && iy < IH && ix >= 0 && ix < IW) ? xp[iy * IW + ix] : 0.f;
            }
            *(float4*)&plane[row * 252 + 4 * c4] = v;
        }
        __syncthreads();
        if (s < 31) {
            const float* wg = w + (size_t)(g * 3) * 75 + ic * 25;  // + c3*75 + ky*5 + kx
            #pragma unroll
            for (int iy = 0; iy < 13; ++iy) {
                float a[12];
                *(float4*)&a[0] = *(const float4*)&plane[(8 * t + iy) * 252 + 8 * s + 0];
                *(float4*)&a[4] = *(const float4*)&plane[(8 * t + iy) * 252 + 8 * s + 4];
                *(float4*)&a[8] = *(const float4*)&plane[(8 * t + iy) * 252 + 8 * s + 8];
                #pragma unroll
                for (int r = 0; r < 5; ++r) {
                    const int ky = iy - 2 * r;
                    if (ky < 0 || ky > 4) continue;
                    #pragma unroll
                    for (int c3 = 0; c3 < 3; ++c3) {
                        #pragma unroll
                        for (int kx = 0; kx < 5; ++kx) {
                            const float wv = wg[c3 * 75 + ky * 5 + kx];   // uniform s_load
                            #pragma unroll
                            for (int j = 0; j < 4; ++j)
                                acc[r][j][c3] = fmaf(a[2 * j + kx], wv, acc[r][j][c3]);
                        }
                    }
                }
            }
        }
    }

    // exchange left column (neighbor strip needs our col 0)
    __syncthreads();
    float* ex = plane;
    if (s < 31) {
        #pragma unroll
        for (int c3 = 0; c3 < 3; ++c3)
            #pragma unroll
            for (int r = 0; r < 5; ++r)
                ex[(((g << 2) | t) * 32 + s) * 16 + c3 * 5 + r] = acc[r][0][c3];
    }
    __syncthreads();
    if (s < 31) {
        #pragma unroll
        for (int c3 = 0; c3 < 3; ++c3) {
            float nb[5];
            #pragma unroll
            for (int r = 0; r < 5; ++r)
                nb[r] = ex[(((g << 2) | t) * 32 + s + 1) * 16 + c3 * 5 + r];
            const int c = g * 3 + c3;
            #pragma unroll
            for (int pr = 0; pr < 4; ++pr) {
                const int prow = p0 + 4 * t + pr;
                if (prow < P1H) {
                    #pragma unroll
                    for (int pj = 0; pj < 4; ++pj) {
                        const int pcol = 4 * s + pj;
                        if (pcol < P1W) {
                            const float v0 = fmaxf(acc[pr][pj][c3], acc[pr + 1][pj][c3]);
                            const float v1 = (pj < 3) ? fmaxf(acc[pr][pj + 1][c3], acc[pr + 1][pj + 1][c3])
                                                      : fmaxf(nb[pr], nb[pr + 1]);
                            out[((size_t)(b * C1 + c) * P1H + prow) * P1W + pcol] =
                                fmaxf(fmaxf(v0, v1), 0.f);
                        }
                    }
                }
            }
        }
    }
}

// ============ conv2 (6->15, k3, s2, p1) + ReLU + MaxPool2s1 -> padded flat A ============
// grid: 384 = 64 b * 3 cgroups(5ch) * 2 rowhalves (XCD-swizzled) ; block 128
// thread: tl = tid>>4 (0..7 local row tile), s = tid&15 (col strip)
__global__ __launch_bounds__(128) void conv2_pool(const float* __restrict__ p1,
        const float* __restrict__ w, const float* __restrict__ bias,
        float* __restrict__ A) {
    __shared__ float plane[67 * 132];
    const int bid = blockIdx.x;
    const int swz = (bid & 7) * 48 + (bid >> 3);   // 384 = 8 XCD * 48
    const int b   = swz / 6;
    const int r6  = swz - 6 * b;
    const int g   = r6 >> 1;                        // 0..2 (5 out-ch each)
    const int rh  = r6 & 1;                         // row half
    const int tid = threadIdx.x;
    const int tl  = tid >> 4;                       // 0..7
    const int s   = tid & 15;
    const int tg  = 8 * rh + tl;                    // global row tile 0..15

    float acc[5][4][5];
    #pragma unroll
    for (int c5 = 0; c5 < 5; ++c5) {
        const float bz = bias[g * 5 + c5];
        #pragma unroll
        for (int r = 0; r < 5; ++r)
            #pragma unroll
            for (int j = 0; j < 4; ++j)
                acc[r][j][c5] = bz;
    }

    for (int ic = 0; ic < 6; ++ic) {
        __syncthreads();
        // stage rows iy = 64*rh - 1 + lrow (lrow 0..66), cols ix = col-1 (col 0..131, 125 valid)
        const float* xp = p1 + (size_t)(b * C1 + ic) * (P1H * P1W);
        for (int i = tid; i < 67 * 33; i += 128) {
            const int lrow = i / 33;
            const int c4   = i - lrow * 33;
            const int iy   = 64 * rh - 1 + lrow;
            float4 v;
            float* vv = (float*)&v;
            #pragma unroll
            for (int e = 0; e < 4; ++e) {
                const int ix = 4 * c4 + e - 1;
                vv[e] = (iy >= 0 && iy < P1H && ix >= 0 && ix < P1W) ? xp[iy * P1W + ix] : 0.f;
            }
            *(float4*)&plane[lrow * 132 + 4 * c4] = v;
        }
        __syncthreads();
        const float* wg = w + (size_t)(g * 5) * 54 + ic * 9;   // + c5*54 + ky*3 + kx
        #pragma unroll
        for (int iy = 0; iy < 11; ++iy) {
            float a[12];
            *(float4*)&a[0] = *(const float4*)&plane[(8 * tl + iy) * 132 + 8 * s + 0];
            *(float4*)&a[4] = *(const float4*)&plane[(8 * tl + iy) * 132 + 8 * s + 4];
            *(float4*)&a[8] = *(const float4*)&plane[(8 * tl + iy) * 132 + 8 * s + 8];
            #pragma unroll
            for (int r = 0; r < 5; ++r) {
                const int ky = iy - 2 * r;
                if (ky < 0 || ky > 2) continue;
                #pragma unroll
                for (int c5 = 0; c5 < 5; ++c5) {
                    #pragma unroll
                    for (int kx = 0; kx < 3; ++kx) {
                        const float wv = wg[c5 * 54 + ky * 3 + kx];   // uniform s_load
                        #pragma unroll
                        for (int j = 0; j < 4; ++j)
                            acc[r][j][c5] = fmaf(a[2 * j + kx], wv, acc[r][j][c5]);
                    }
                }
            }
        }
    }

    __syncthreads();
    float* ex = plane;
    #pragma unroll
    for (int c5 = 0; c5 < 5; ++c5)
        #pragma unroll
        for (int r = 0; r < 5; ++r)
            ex[tid * 26 + c5 * 5 + r] = acc[r][0][c5];
    __syncthreads();
    #pragma unroll
    for (int c5 = 0; c5 < 5; ++c5) {
        float nb[5];
        #pragma unroll
        for (int r = 0; r < 5; ++r)
            nb[r] = ex[(tid + 1) * 26 + c5 * 5 + r];   // garbage for s==15, masked below
        const int c = g * 5 + c5;
        #pragma unroll
        for (int pr = 0; pr < 4; ++pr) {
            const int prow = 4 * tg + pr;
            if (prow < P2H) {
                #pragma unroll
                for (int pj = 0; pj < 4; ++pj) {
                    const int pcol = 4 * s + pj;
                    if (pcol < P2W) {
                        const float v0 = fmaxf(acc[pr][pj][c5], acc[pr + 1][pj][c5]);
                        const float v1 = (pj < 3) ? fmaxf(acc[pr][pj + 1][c5], acc[pr + 1][pj + 1][c5])
                                                  : fmaxf(nb[pr], nb[pr + 1]);
                        A[(size_t)b * KPAD + c * 3721 + prow * 61 + pcol] =
                            fmaxf(fmaxf(v0, v1), 0.f);
                    }
                }
            }
        }
    }
    if (g == 0 && rh == 0 && tid == 0) A[(size_t)b * KPAD + KFC] = 0.f;   // pad element
}

// ============ fc1 split-K stage 1 (raw W via uniform scalar loads) ============
__global__ __launch_bounds__(256) void fc1_s1(const float* __restrict__ A,
        const float* __restrict__ W, float* __restrict__ part) {
    __shared__ float sA[64 * 252];
    const int chunk = blockIdx.x;
    const int k0 = chunk * KC;
    const int tid = threadIdx.x;

    for (int i = tid; i < 64 * 62; i += 256) {
        const int row = i / 62;
        const int c4  = i - row * 62;
        const int k   = k0 + 4 * c4;
        float4 v;
        if (k + 3 < KPAD) {
            v = *(const float4*)&A[(size_t)row * KPAD + k];
        } else {
            float* vv = (float*)&v;
            #pragma unroll
            for (int e = 0; e < 4; ++e)
                vv[e] = (k + e < KPAD) ? A[(size_t)row * KPAD + k + e] : 0.f;
        }
        *(float4*)&sA[row * 252 + 4 * c4] = v;
    }
    __syncthreads();

    const int lane = tid & 63;
    const int wv   = tid >> 6;
    const float* sArow = sA + lane * 252;

    for (int p = 0; p < 5; ++p) {
        const int o0 = __builtin_amdgcn_readfirstlane(p * 24 + wv * 6);
        const float* w0 = W + (size_t)o0 * KFC + k0;
        float acc[6] = {0.f, 0.f, 0.f, 0.f, 0.f, 0.f};
        if (chunk < NCH - 1) {
            for (int k4 = 0; k4 < 62; ++k4) {
                const float4 a = *(const float4*)&sArow[4 * k4];
                #pragma unroll
                for (int oi = 0; oi < 6; ++oi) {
                    const float* wr = w0 + (size_t)oi * KFC + 4 * k4;   // uniform -> s_loads
                    acc[oi] = fmaf(a.x, wr[0], fmaf(a.y, wr[1], fmaf(a.z, wr[2], fmaf(a.w, wr[3], acc[oi]))));
                }
            }
        } else {
            for (int k4 = 0; k4 < 3; ++k4) {       // 55800..55811
                const float4 a = *(const float4*)&sArow[4 * k4];
                #pragma unroll
                for (int oi = 0; oi < 6; ++oi) {
                    const float* wr = w0 + (size_t)oi * KFC + 4 * k4;
                    acc[oi] = fmaf(a.x, wr[0], fmaf(a.y, wr[1], fmaf(a.z, wr[2], fmaf(a.w, wr[3], acc[oi]))));
                }
            }
            #pragma unroll
            for (int e = 12; e < 15; ++e) {        // 55812..55814
                const float ae = sArow[e];
                #pragma unroll
                for (int oi = 0; oi < 6; ++oi)
                    acc[oi] = fmaf(ae, w0[(size_t)oi * KFC + e], acc[oi]);
            }
        }
        const size_t base = ((size_t)chunk * NFC1 + o0) * 64 + lane;
        #pragma unroll
        for (int oi = 0; oi < 6; ++oi)
            part[base + (size_t)oi * 64] = acc[oi];
    }
}

__global__ __launch_bounds__(256) void fc1_s2(const float* __restrict__ part,
        const float* __restrict__ bias, float* __restrict__ out) {
    const int idx = blockIdx.x * 256 + threadIdx.x;   // 7680
    const int o = idx >> 6;
    const int b = idx & 63;
    float s = 0.f;
    for (int c = 0; c < NCH; ++c) s += part[(size_t)c * (NFC1 * 64) + idx];
    out[b * NFC1 + o] = fmaxf(s + bias[o], 0.f);
}

// ============ tail: fc2 rows 0..3 + fidelity kernel + classifier + softmax ============
__global__ __launch_bounds__(64) void tail_k(const float* __restrict__ fc1o,
        const float* __restrict__ fc2w, const float* __restrict__ fc2b,
        const float* __restrict__ centers,
        const float* __restrict__ w1, const float* __restrict__ b1,
        const float* __restrict__ w2, const float* __restrict__ b2,
        const float* __restrict__ w3, const float* __restrict__ b3,
        float* __restrict__ out) {
    const int b = blockIdx.x;
    const int lane = threadIdx.x;
    __shared__ float h[120];
    __shared__ float feat[4];
    __shared__ float bufA[64];
    __shared__ float bufB[64];

    for (int i = lane; i < NFC1; i += 64) h[i] = fc1o[b * NFC1 + i];
    __syncthreads();

    const int j = lane >> 4, p = lane & 15;
    float sv = 0.f;
    for (int o = p; o < NFC1; o += 16) sv = fmaf(fc2w[j * NFC1 + o], h[o], sv);
    #pragma unroll
    for (int off = 8; off; off >>= 1) sv += __shfl_xor(sv, off, 16);
    if (p == 0) feat[j] = fmaxf(sv + fc2b[j], 0.f);
    __syncthreads();

    float prod = 1.f;
    #pragma unroll
    for (int i = 0; i < 4; ++i) prod *= cosf(0.5f * (feat[i] - centers[lane * 84 + i]));
    bufA[lane] = fabsf(prod);
    __syncthreads();

    float s1 = b1[lane];
    for (int jj = 0; jj < 64; ++jj) s1 = fmaf(w1[lane * 64 + jj], bufA[jj], s1);
    bufB[lane] = fmaxf(s1, 0.f);
    __syncthreads();

    float s2 = b2[lane];
    for (int jj = 0; jj < 64; ++jj) s2 = fmaf(w2[lane * 64 + jj], bufB[jj], s2);
    bufA[lane] = fmaxf(s2, 0.f);
    __syncthreads();

    if (lane < 2) {
        float s3 = b3[lane];
        for (int jj = 0; jj < 64; ++jj) s3 = fmaf(w3[lane * 64 + jj], bufA[jj], s3);
        const float other = __shfl_xor(s3, 1, 2);
        const float m = fmaxf(s3, other);
        const float e = expf(s3 - m), eo = expf(other - m);
        out[b * 2 + lane] = e / (e + eo);
    }
}

// ---------------- launcher ----------------
extern "C" void kernel_launch(void* const* d_in, const int* in_sizes, int n_in,
                              void* d_out, int out_size, void* d_ws, size_t ws_size,
                              hipStream_t stream) {
    const float* x       = (const float*)d_in[0];
    const float* conv1_w = (const float*)d_in[1];
    const float* conv1_b = (const float*)d_in[2];
    const float* conv2_w = (const float*)d_in[3];
    const float* conv2_b = (const float*)d_in[4];
    const float* fc1_w   = (const float*)d_in[5];
    const float* fc1_b   = (const float*)d_in[6];
    const float* fc2_w   = (const float*)d_in[7];
    const float* fc2_b   = (const float*)d_in[8];
    const float* centers = (const float*)d_in[9];
    const float* cls_w1  = (const float*)d_in[10];
    const float* cls_b1  = (const float*)d_in[11];
    const float* cls_w2  = (const float*)d_in[12];
    const float* cls_b2  = (const float*)d_in[13];
    const float* cls_w3  = (const float*)d_in[14];
    const float* cls_b3  = (const float*)d_in[15];
    float* ws   = (float*)d_ws;
    float* outp = (float*)d_out;

    float* p1   = ws + oP1;
    float* Abuf = ws + oA;
    float* partb = ws + oPART;
    float* fc1o = ws + oFC1;

    hipLaunchKernelGGL(conv1_pool, dim3(512), dim3(256), 0, stream, x, conv1_w, conv1_b, p1);
    hipLaunchKernelGGL(conv2_pool, dim3(384), dim3(128), 0, stream, p1, conv2_w, conv2_b, Abuf);
    hipLaunchKernelGGL(fc1_s1, dim3(NCH), dim3(256), 0, stream, Abuf, fc1_w, partb);
    hipLaunchKernelGGL(fc1_s2, dim3(30), dim3(256), 0, stream, partb, fc1_b, fc1o);
    hipLaunchKernelGGL(tail_k, dim3(BATCH), dim3(64), 0, stream,
                       fc1o, fc2_w, fc2_b, centers, cls_w1, cls_b1, cls_w2, cls_b2, cls_w3, cls_b3, outp);
}

// Round 7
// 221.169 us; speedup vs baseline: 2.4501x; 1.1276x over previous
//
#include <hip/hip_runtime.h>
#include <hip/hip_bf16.h>

// ---------------- problem dims ----------------
#define BATCH 64
#define C1 6
#define IH 250
#define IW 250
#define P1H 123
#define P1W 123
#define C2 15
#define P2H 61
#define P2W 61
#define KFC 55815          // 15*61*61
#define KPAD 55816         // padded feature row stride (A)
#define NFC1 120
#define CH 128             // fc1 K-chunk
#define NCH 437            // ceil(55815/128)

// workspace offsets (floats)
#define oP1   ((size_t)0)                       // 64*6*123*123 = 5,809,536
#define oA    ((size_t)5809536)                 // 64*55816     = 3,572,224
#define oPART ((size_t)(5809536+3572224))       // 437*7680     = 3,356,160
#define oFC1  ((size_t)(5809536+3572224+3356160)) // 7680

// ============ conv1 (3->6, k5, s2, p1) + ReLU + MaxPool2s1, fused [r2-VERBATIM] ============
// grid: 512 = 64 b * 8 row-groups ; block 256
__global__ __launch_bounds__(256) void conv1_pool(const float* __restrict__ x,
        const float* __restrict__ w, const float* __restrict__ bias,
        float* __restrict__ out) {
    __shared__ float plane[37 * 252];
    const int tid = threadIdx.x;
    const int b  = blockIdx.x >> 3;
    const int G  = blockIdx.x & 7;
    const int p0 = G * 16;                     // first pool row of block
    const int g  = __builtin_amdgcn_readfirstlane(tid >> 7);
    const int t  = (tid >> 5) & 3;
    const int s  = tid & 31;

    float acc[5][4][3];
    #pragma unroll
    for (int c3 = 0; c3 < 3; ++c3) {
        const float bz = bias[g * 3 + c3];     // uniform -> s_load
        #pragma unroll
        for (int r = 0; r < 5; ++r)
            #pragma unroll
            for (int j = 0; j < 4; ++j)
                acc[r][j][c3] = bz;
    }

    for (int ic = 0; ic < 3; ++ic) {
        __syncthreads();
        const float* xp = x + (size_t)(b * 3 + ic) * (IH * IW);
        for (int i = tid; i < 37 * 63; i += 256) {
            const int row = i / 63;
            const int c4  = i - row * 63;
            const int iy  = 2 * p0 - 1 + row;
            float4 v;
            float* vv = (float*)&v;
            #pragma unroll
            for (int e = 0; e < 4; ++e) {
                const int ix = 4 * c4 + e - 1;
                vv[e] = (iy >= 0 && iy < IH && ix >= 0 && ix < IW) ? xp[iy * IW + ix] : 0.f;
            }
            *(float4*)&plane[row * 252 + 4 * c4] = v;
        }
        __syncthreads();
        if (s < 31) {
            const float* wg = w + (size_t)(g * 3) * 75 + ic * 25;  // + c3*75 + ky*5 + kx
            #pragma unroll
            for (int iy = 0; iy < 13; ++iy) {
                float a[12];
                *(float4*)&a[0] = *(const float4*)&plane[(8 * t + iy) * 252 + 8 * s + 0];
                *(float4*)&a[4] = *(const float4*)&plane[(8 * t + iy) * 252 + 8 * s + 4];
                *(float4*)&a[8] = *(const float4*)&plane[(8 * t + iy) * 252 + 8 * s + 8];
                #pragma unroll
                for (int r = 0; r < 5; ++r) {
                    const int ky = iy - 2 * r;
                    if (ky < 0 || ky > 4) continue;
                    #pragma unroll
                    for (int c3 = 0; c3 < 3; ++c3) {
                        #pragma unroll
                        for (int kx = 0; kx < 5; ++kx) {
                            const float wv = wg[c3 * 75 + ky * 5 + kx];   // uniform s_load
                            #pragma unroll
                            for (int j = 0; j < 4; ++j)
                                acc[r][j][c3] = fmaf(a[2 * j + kx], wv, acc[r][j][c3]);
                        }
                    }
                }
            }
        }
    }

    __syncthreads();
    float* ex = plane;
    if (s < 31) {
        #pragma unroll
        for (int c3 = 0; c3 < 3; ++c3)
            #pragma unroll
            for (int r = 0; r < 5; ++r)
                ex[(((g << 2) | t) * 32 + s) * 16 + c3 * 5 + r] = acc[r][0][c3];
    }
    __syncthreads();
    if (s < 31) {
        #pragma unroll
        for (int c3 = 0; c3 < 3; ++c3) {
            float nb[5];
            #pragma unroll
            for (int r = 0; r < 5; ++r)
                nb[r] = ex[(((g << 2) | t) * 32 + s + 1) * 16 + c3 * 5 + r];
            const int c = g * 3 + c3;
            #pragma unroll
            for (int pr = 0; pr < 4; ++pr) {
                const int prow = p0 + 4 * t + pr;
                if (prow < P1H) {
                    #pragma unroll
                    for (int pj = 0; pj < 4; ++pj) {
                        const int pcol = 4 * s + pj;
                        if (pcol < P1W) {
                            const float v0 = fmaxf(acc[pr][pj][c3], acc[pr + 1][pj][c3]);
                            const float v1 = (pj < 3) ? fmaxf(acc[pr][pj + 1][c3], acc[pr + 1][pj + 1][c3])
                                                      : fmaxf(nb[pr], nb[pr + 1]);
                            out[((size_t)(b * C1 + c) * P1H + prow) * P1W + pcol] =
                                fmaxf(fmaxf(v0, v1), 0.f);
                        }
                    }
                }
            }
        }
    }
}

// ============ conv2 (6->15, k3, s2, p1) + ReLU + MaxPool2s1 -> padded flat A [r2-VERBATIM] ============
// grid: 384 = 64 b * 3 cgroups(5ch) * 2 rowhalves (XCD-swizzled) ; block 128
__global__ __launch_bounds__(128) void conv2_pool(const float* __restrict__ p1,
        const float* __restrict__ w, const float* __restrict__ bias,
        float* __restrict__ A) {
    __shared__ float plane[67 * 132];
    const int bid = blockIdx.x;
    const int swz = (bid & 7) * 48 + (bid >> 3);   // 384 = 8 XCD * 48
    const int b   = swz / 6;
    const int r6  = swz - 6 * b;
    const int g   = r6 >> 1;                        // 0..2 (5 out-ch each)
    const int rh  = r6 & 1;                         // row half
    const int tid = threadIdx.x;
    const int tl  = tid >> 4;                       // 0..7
    const int s   = tid & 15;
    const int tg  = 8 * rh + tl;                    // global row tile 0..15

    float acc[5][4][5];
    #pragma unroll
    for (int c5 = 0; c5 < 5; ++c5) {
        const float bz = bias[g * 5 + c5];
        #pragma unroll
        for (int r = 0; r < 5; ++r)
            #pragma unroll
            for (int j = 0; j < 4; ++j)
                acc[r][j][c5] = bz;
    }

    for (int ic = 0; ic < 6; ++ic) {
        __syncthreads();
        const float* xp = p1 + (size_t)(b * C1 + ic) * (P1H * P1W);
        for (int i = tid; i < 67 * 33; i += 128) {
            const int lrow = i / 33;
            const int c4   = i - lrow * 33;
            const int iy   = 64 * rh - 1 + lrow;
            float4 v;
            float* vv = (float*)&v;
            #pragma unroll
            for (int e = 0; e < 4; ++e) {
                const int ix = 4 * c4 + e - 1;
                vv[e] = (iy >= 0 && iy < P1H && ix >= 0 && ix < P1W) ? xp[iy * P1W + ix] : 0.f;
            }
            *(float4*)&plane[lrow * 132 + 4 * c4] = v;
        }
        __syncthreads();
        const float* wg = w + (size_t)(g * 5) * 54 + ic * 9;   // + c5*54 + ky*3 + kx
        #pragma unroll
        for (int iy = 0; iy < 11; ++iy) {
            float a[12];
            *(float4*)&a[0] = *(const float4*)&plane[(8 * tl + iy) * 132 + 8 * s + 0];
            *(float4*)&a[4] = *(const float4*)&plane[(8 * tl + iy) * 132 + 8 * s + 4];
            *(float4*)&a[8] = *(const float4*)&plane[(8 * tl + iy) * 132 + 8 * s + 8];
            #pragma unroll
            for (int r = 0; r < 5; ++r) {
                const int ky = iy - 2 * r;
                if (ky < 0 || ky > 2) continue;
                #pragma unroll
                for (int c5 = 0; c5 < 5; ++c5) {
                    #pragma unroll
                    for (int kx = 0; kx < 3; ++kx) {
                        const float wv = wg[c5 * 54 + ky * 3 + kx];   // uniform s_load
                        #pragma unroll
                        for (int j = 0; j < 4; ++j)
                            acc[r][j][c5] = fmaf(a[2 * j + kx], wv, acc[r][j][c5]);
                    }
                }
            }
        }
    }

    __syncthreads();
    float* ex = plane;
    #pragma unroll
    for (int c5 = 0; c5 < 5; ++c5)
        #pragma unroll
        for (int r = 0; r < 5; ++r)
            ex[tid * 26 + c5 * 5 + r] = acc[r][0][c5];
    __syncthreads();
    #pragma unroll
    for (int c5 = 0; c5 < 5; ++c5) {
        float nb[5];
        #pragma unroll
        for (int r = 0; r < 5; ++r)
            nb[r] = ex[(tid + 1) * 26 + c5 * 5 + r];   // garbage for s==15, masked below
        const int c = g * 5 + c5;
        #pragma unroll
        for (int pr = 0; pr < 4; ++pr) {
            const int prow = 4 * tg + pr;
            if (prow < P2H) {
                #pragma unroll
                for (int pj = 0; pj < 4; ++pj) {
                    const int pcol = 4 * s + pj;
                    if (pcol < P2W) {
                        const float v0 = fmaxf(acc[pr][pj][c5], acc[pr + 1][pj][c5]);
                        const float v1 = (pj < 3) ? fmaxf(acc[pr][pj + 1][c5], acc[pr + 1][pj + 1][c5])
                                                  : fmaxf(nb[pr], nb[pr + 1]);
                        A[(size_t)b * KPAD + c * 3721 + prow * 61 + pcol] =
                            fmaxf(fmaxf(v0, v1), 0.f);
                    }
                }
            }
        }
    }
    if (g == 0 && rh == 0 && tid == 0) A[(size_t)b * KPAD + KFC] = 0.f;   // pad element
}

// ============ fc1 split-K (VALU, f32): part[c][o][b] ============
// grid 437 ; block 512 = 8 waves ; lane = batch row, wave = 15 outputs
__global__ __launch_bounds__(512) void fc1_s1(const float* __restrict__ A,
        const float* __restrict__ W, float* __restrict__ part) {
    __shared__ float sA[64 * 132];        // 33 KB
    const int cBlk = blockIdx.x;
    const int k0 = cBlk * CH;
    const int tid = threadIdx.x;

    #pragma unroll
    for (int it = 0; it < 4; ++it) {      // 2048 float4s = 64 rows x 32
        const int f4 = tid + 512 * it;
        const int row = f4 >> 5;
        const int c4 = f4 & 31;
        const int k = k0 + 4 * c4;
        float4 v = make_float4(0.f, 0.f, 0.f, 0.f);
        if (k + 3 <= KFC)                 // covers k..k+3; elem KFC is the zero pad
            v = *(const float4*)(A + (size_t)row * KPAD + k);
        *(float4*)&sA[row * 132 + 4 * c4] = v;
    }
    __syncthreads();

    const int lane = tid & 63;            // batch row
    const int wv = tid >> 6;              // 0..7
    const int o0 = wv * 15;
    const float* wr0 = W + (size_t)o0 * KFC + k0;
    float acc[15];
    #pragma unroll
    for (int oi = 0; oi < 15; ++oi) acc[oi] = 0.f;

    if (cBlk != NCH - 1) {
        for (int k4 = 0; k4 < 32; ++k4) {
            const float4 a4 = *(const float4*)&sA[lane * 132 + 4 * k4];
            #pragma unroll
            for (int oi = 0; oi < 15; ++oi) {
                const float* wr = wr0 + (size_t)oi * KFC + 4 * k4;   // wave-uniform
                acc[oi] = fmaf(a4.x, wr[0], fmaf(a4.y, wr[1],
                          fmaf(a4.z, wr[2], fmaf(a4.w, wr[3], acc[oi]))));
            }
        }
    } else {
        // k0 = 55808; valid k = 55808..55814 (7 elems)
        const float4 a4 = *(const float4*)&sA[lane * 132];
        const float a5 = sA[lane * 132 + 4];
        const float a6 = sA[lane * 132 + 5];
        const float a7 = sA[lane * 132 + 6];
        #pragma unroll
        for (int oi = 0; oi < 15; ++oi) {
            const float* wr = wr0 + (size_t)oi * KFC;
            float sv = fmaf(a4.x, wr[0], fmaf(a4.y, wr[1],
                       fmaf(a4.z, wr[2], a4.w * wr[3])));
            acc[oi] = fmaf(a5, wr[4], fmaf(a6, wr[5], fmaf(a7, wr[6], sv)));
        }
    }
    #pragma unroll
    for (int oi = 0; oi < 15; ++oi)
        part[((size_t)cBlk * NFC1 + o0 + oi) * 64 + lane] = acc[oi];
}

// ============ fc1 stage2: full reduce over 437 chunks [r2 structure] ============
__global__ __launch_bounds__(256) void fc1_s2(const float* __restrict__ part,
        const float* __restrict__ bias, float* __restrict__ out) {
    const int idx = blockIdx.x * 256 + threadIdx.x;   // 7680
    const int o = idx >> 6;
    const int b = idx & 63;
    float s = 0.f;
    for (int c = 0; c < NCH; ++c) s += part[(size_t)c * 7680 + idx];
    out[b * NFC1 + o] = fmaxf(s + bias[o], 0.f);
}

// ============ tail [r2-VERBATIM] ============
__global__ __launch_bounds__(64) void tail_k(const float* __restrict__ fc1o,
        const float* __restrict__ fc2w, const float* __restrict__ fc2b,
        const float* __restrict__ centers,
        const float* __restrict__ w1, const float* __restrict__ b1,
        const float* __restrict__ w2, const float* __restrict__ b2,
        const float* __restrict__ w3, const float* __restrict__ b3,
        float* __restrict__ out) {
    const int b = blockIdx.x;
    const int lane = threadIdx.x;
    __shared__ float h[120];
    __shared__ float feat[4];
    __shared__ float bufA[64];
    __shared__ float bufB[64];

    for (int i = lane; i < NFC1; i += 64) h[i] = fc1o[b * NFC1 + i];
    __syncthreads();

    const int j = lane >> 4, p = lane & 15;
    float sv = 0.f;
    for (int o = p; o < NFC1; o += 16) sv = fmaf(fc2w[j * NFC1 + o], h[o], sv);
    #pragma unroll
    for (int off = 8; off; off >>= 1) sv += __shfl_xor(sv, off, 16);
    if (p == 0) feat[j] = fmaxf(sv + fc2b[j], 0.f);
    __syncthreads();

    float prod = 1.f;
    #pragma unroll
    for (int i = 0; i < 4; ++i) prod *= cosf(0.5f * (feat[i] - centers[lane * 84 + i]));
    bufA[lane] = fabsf(prod);
    __syncthreads();

    float s1 = b1[lane];
    for (int jj = 0; jj < 64; ++jj) s1 = fmaf(w1[lane * 64 + jj], bufA[jj], s1);
    bufB[lane] = fmaxf(s1, 0.f);
    __syncthreads();

    float s2 = b2[lane];
    for (int jj = 0; jj < 64; ++jj) s2 = fmaf(w2[lane * 64 + jj], bufB[jj], s2);
    bufA[lane] = fmaxf(s2, 0.f);
    __syncthreads();

    if (lane < 2) {
        float s3 = b3[lane];
        for (int jj = 0; jj < 64; ++jj) s3 = fmaf(w3[lane * 64 + jj], bufA[jj], s3);
        const float other = __shfl_xor(s3, 1, 2);
        const float m = fmaxf(s3, other);
        const float e = expf(s3 - m), eo = expf(other - m);
        out[b * 2 + lane] = e / (e + eo);
    }
}

// ---------------- launcher ----------------
extern "C" void kernel_launch(void* const* d_in, const int* in_sizes, int n_in,
                              void* d_out, int out_size, void* d_ws, size_t ws_size,
                              hipStream_t stream) {
    const float* x       = (const float*)d_in[0];
    const float* conv1_w = (const float*)d_in[1];
    const float* conv1_b = (const float*)d_in[2];
    const float* conv2_w = (const float*)d_in[3];
    const float* conv2_b = (const float*)d_in[4];
    const float* fc1_w   = (const float*)d_in[5];
    const float* fc1_b   = (const float*)d_in[6];
    const float* fc2_w   = (const float*)d_in[7];
    const float* fc2_b   = (const float*)d_in[8];
    const float* centers = (const float*)d_in[9];
    const float* cls_w1  = (const float*)d_in[10];
    const float* cls_b1  = (const float*)d_in[11];
    const float* cls_w2  = (const float*)d_in[12];
    const float* cls_b2  = (const float*)d_in[13];
    const float* cls_w3  = (const float*)d_in[14];
    const float* cls_b3  = (const float*)d_in[15];
    float* ws   = (float*)d_ws;
    float* outp = (float*)d_out;

    float* p1    = ws + oP1;
    float* Abuf  = ws + oA;
    float* partb = ws + oPART;
    float* fc1o  = ws + oFC1;

    hipLaunchKernelGGL(conv1_pool, dim3(512), dim3(256), 0, stream, x, conv1_w, conv1_b, p1);
    hipLaunchKernelGGL(conv2_pool, dim3(384), dim3(128), 0, stream, p1, conv2_w, conv2_b, Abuf);
    hipLaunchKernelGGL(fc1_s1, dim3(NCH), dim3(512), 0, stream, Abuf, fc1_w, partb);
    hipLaunchKernelGGL(fc1_s2, dim3(30), dim3(256), 0, stream, partb, fc1_b, fc1o);
    hipLaunchKernelGGL(tail_k, dim3(64), dim3(64), 0, stream,
                       fc1o, fc2_w, fc2_b, centers,
                       cls_w1, cls_b1, cls_w2, cls_b2, cls_w3, cls_b3, outp);
}

// Round 8
// 136.262 us; speedup vs baseline: 3.9768x; 1.6231x over previous
//
#include <hip/hip_runtime.h>
#include <hip/hip_bf16.h>

typedef float float4a __attribute__((ext_vector_type(4), aligned(4)));
typedef float float2a __attribute__((ext_vector_type(2), aligned(4)));

// ---------------- dims ----------------
#define P1W_PAD 128            // p1 row stride (f32), cols 123..127 zero
#define APAD 56064             // A row stride (f32), elems 55815.. zero
#define KFC 55815
#define CH 128                 // fc1 K-chunk
#define NCH 437                // ceil(55815/128); 436*128 = 55808
#define NFC1 120

// ws byte offsets
#define oP1B   ((size_t)0)            // 64*6*123*128*4 = 24,182,784
#define oAB    ((size_t)24182784)     // 64*56064*4     = 14,352,384
#define oPARTB ((size_t)38535168)     // 437*7680*4     = 13,424,640
#define oFC1B  ((size_t)51959808)     // 7680*4
// ============ conv1 (3->6,k5,s2,p1)+ReLU+pool2s1 -> p1 f32[64][6][123][128] ============
// grid (18, 64) block 256 ; t=tid>>5 conv row (7G+t), s=tid&31 -> cols 4s..4s+3 (s<31)
__global__ __launch_bounds__(256) void conv1_pool(const float* __restrict__ x,
        const float* __restrict__ w, const float* __restrict__ bias,
        float* __restrict__ p1) {
    __shared__ float ex[8 * 6 * 128];     // 24.6 KB
    const int tid = threadIdx.x;
    const int G = blockIdx.x;
    const int b = blockIdx.y;
    const int t = tid >> 5;
    const int s = tid & 31;
    const int r = 7 * G + t;
    const bool act = (r < 124) && (s < 31);

    if (act) {
        float acc[6][4];
        #pragma unroll
        for (int c = 0; c < 6; ++c) {
            const float bz = bias[c];
            #pragma unroll
            for (int j = 0; j < 4; ++j) acc[c][j] = bz;
        }
        for (int ic = 0; ic < 3; ++ic) {
            const float* xpl = x + (size_t)(b * 3 + ic) * 62500;
            #pragma unroll
            for (int ky = 0; ky < 5; ++ky) {
                const int iy = 2 * r - 1 + ky;
                if (iy < 0) continue;                       // top pad (bottom never hit)
                const float* rp = xpl + iy * 250 + 8 * s;
                float a[11];
                a[0] = (s > 0) ? rp[-1] : 0.f;              // left pad
                *(float4a*)&a[1] = *(const float4a*)rp;
                *(float4a*)&a[5] = *(const float4a*)(rp + 4);
                *(float2a*)&a[9] = *(const float2a*)(rp + 8);
                const float* wb = w + ic * 25 + ky * 5;     // + c*75 + kx (uniform s_loads)
                #pragma unroll
                for (int c = 0; c < 6; ++c) {
                    #pragma unroll
                    for (int kx = 0; kx < 5; ++kx) {
                        const float wv = wb[c * 75 + kx];
                        #pragma unroll
                        for (int j = 0; j < 4; ++j)
                            acc[c][j] = fmaf(a[2 * j + kx], wv, acc[c][j]);
                    }
                }
            }
        }
        #pragma unroll
        for (int c = 0; c < 6; ++c)
            *(float4*)&ex[(t * 6 + c) * 128 + 4 * s] = *(float4*)&acc[c][0];
    }
    __syncthreads();
    const int np = min(7, 123 - 7 * G);                     // pool rows this block
    for (int idx = tid; idx < np * 768; idx += 256) {       // 768 = 6*128
        const int p   = idx / 768;
        const int rem = idx - p * 768;                      // FIX: was idx & 767 (768 != 2^n)
        const int c   = rem >> 7;
        const int pc  = rem & 127;
        float v = 0.f;
        if (pc < 123) {
            const float* r0 = &ex[((p    ) * 6 + c) * 128 + pc];
            const float* r1 = &ex[((p + 1) * 6 + c) * 128 + pc];
            v = fmaxf(fmaxf(fmaxf(r0[0], r0[1]), fmaxf(r1[0], r1[1])), 0.f);
        }
        p1[((size_t)(b * 6 + c) * 123 + (7 * G + p)) * P1W_PAD + pc] = v;
    }
}

// ============ conv2 (6->15,k3,s2,p1)+ReLU+pool2s1 -> A f32[64][56064] ============
// grid (5, 64) block 256 ; t=tid>>4 conv row (15G+t), s=tid&15 -> cols 4s..4s+3
__global__ __launch_bounds__(256) void conv2_pool(const float* __restrict__ p1,
        const float* __restrict__ w, const float* __restrict__ bias,
        float* __restrict__ A) {
    __shared__ float ex[16 * 15 * 64];    // 61.4 KB
    const int tid = threadIdx.x;
    const int G = blockIdx.x;
    const int b = blockIdx.y;
    const int t = tid >> 4;
    const int s = tid & 15;
    const int r = 15 * G + t;
    const bool act = (r < 62);

    if (act) {
        float acc[15][4];
        #pragma unroll
        for (int c = 0; c < 15; ++c) {
            const float bz = bias[c];
            #pragma unroll
            for (int j = 0; j < 4; ++j) acc[c][j] = bz;
        }
        for (int ic = 0; ic < 6; ++ic) {
            const float* pl = p1 + (size_t)(b * 6 + ic) * 123 * P1W_PAD;
            #pragma unroll
            for (int ky = 0; ky < 3; ++ky) {
                const int iy = 2 * r - 1 + ky;
                if (iy < 0 || iy > 122) continue;
                const float* rp = pl + iy * P1W_PAD + 8 * s;
                float a[9];
                a[0] = (s > 0) ? rp[-1] : 0.f;              // left pad (cols>=123 are 0)
                *(float4a*)&a[1] = *(const float4a*)rp;
                *(float4a*)&a[5] = *(const float4a*)(rp + 4);
                const float* wb = w + ic * 9 + ky * 3;      // + c*54 + kx (uniform)
                #pragma unroll
                for (int c = 0; c < 15; ++c) {
                    #pragma unroll
                    for (int kx = 0; kx < 3; ++kx) {
                        const float wv = wb[c * 54 + kx];
                        #pragma unroll
                        for (int j = 0; j < 4; ++j)
                            acc[c][j] = fmaf(a[2 * j + kx], wv, acc[c][j]);
                    }
                }
            }
        }
        #pragma unroll
        for (int c = 0; c < 15; ++c)
            *(float4*)&ex[(t * 15 + c) * 64 + 4 * s] = *(float4*)&acc[c][0];
    }
    __syncthreads();
    const int np = min(15, 61 - 15 * G);
    for (int idx = tid; idx < np * 915; idx += 256) {       // 915 = 15*61 (true modulo)
        const int p   = idx / 915;
        const int rem = idx % 915;
        const int c   = rem / 61;
        const int pc  = rem % 61;
        const float* r0 = &ex[((p    ) * 15 + c) * 64 + pc];
        const float* r1 = &ex[((p + 1) * 15 + c) * 64 + pc];
        const float v = fmaxf(fmaxf(r0[0], r0[1]), fmaxf(r1[0], r1[1]));
        A[(size_t)b * APAD + c * 3721 + (15 * G + p) * 61 + pc] = fmaxf(v, 0.f);
    }
    if (G == 0)                                             // zero the K-pad tail
        for (int i2 = tid; i2 < 249; i2 += 256)
            A[(size_t)b * APAD + KFC + i2] = 0.f;
}

// ============ fc1 split-K (VALU, f32): part[c][o][b]  [r7-proven] ============
// grid 437 ; block 512 = 8 waves ; lane = batch row, wave = 15 outputs
__global__ __launch_bounds__(512) void fc1_s1(const float* __restrict__ A,
        const float* __restrict__ W, float* __restrict__ part) {
    __shared__ float sA[64 * 132];        // 33 KB
    const int cBlk = blockIdx.x;
    const int k0 = cBlk * CH;
    const int tid = threadIdx.x;

    #pragma unroll
    for (int it = 0; it < 4; ++it) {      // 2048 float4s = 64 rows x 32
        const int f4 = tid + 512 * it;
        const int row = f4 >> 5;
        const int c4 = f4 & 31;
        const float4 v = *(const float4*)(A + (size_t)row * APAD + k0 + 4 * c4);
        *(float4*)&sA[row * 132 + 4 * c4] = v;   // A pad zeroed through 56064 -> in-bounds
    }
    __syncthreads();

    const int lane = tid & 63;            // batch row
    const int wv = tid >> 6;              // 0..7
    const int o0 = wv * 15;
    const float* wr0 = W + (size_t)o0 * KFC + k0;
    float acc[15];
    #pragma unroll
    for (int oi = 0; oi < 15; ++oi) acc[oi] = 0.f;

    if (cBlk != NCH - 1) {
        for (int k4 = 0; k4 < 32; ++k4) {
            const float4 a4 = *(const float4*)&sA[lane * 132 + 4 * k4];
            #pragma unroll
            for (int oi = 0; oi < 15; ++oi) {
                const float* wr = wr0 + (size_t)oi * KFC + 4 * k4;   // wave-uniform
                acc[oi] = fmaf(a4.x, wr[0], fmaf(a4.y, wr[1],
                          fmaf(a4.z, wr[2], fmaf(a4.w, wr[3], acc[oi]))));
            }
        }
    } else {
        // k0 = 55808; valid k = 55808..55814 (7 elems)
        const float4 a4 = *(const float4*)&sA[lane * 132];
        const float a5 = sA[lane * 132 + 4];
        const float a6 = sA[lane * 132 + 5];
        const float a7 = sA[lane * 132 + 6];
        #pragma unroll
        for (int oi = 0; oi < 15; ++oi) {
            const float* wr = wr0 + (size_t)oi * KFC;
            float sv = fmaf(a4.x, wr[0], fmaf(a4.y, wr[1],
                       fmaf(a4.z, wr[2], a4.w * wr[3])));
            acc[oi] = fmaf(a5, wr[4], fmaf(a6, wr[5], fmaf(a7, wr[6], sv)));
        }
    }
    #pragma unroll
    for (int oi = 0; oi < 15; ++oi)
        part[((size_t)cBlk * NFC1 + o0 + oi) * 64 + lane] = acc[oi];
}

// ============ fc1 stage2: full reduce over 437 chunks [r7-verbatim] ============
__global__ __launch_bounds__(256) void fc1_s2(const float* __restrict__ part,
        const float* __restrict__ bias, float* __restrict__ out) {
    const int idx = blockIdx.x * 256 + threadIdx.x;   // 7680
    const int o = idx >> 6;
    const int b = idx & 63;
    float s = 0.f;
    for (int c = 0; c < NCH; ++c) s += part[(size_t)c * 7680 + idx];
    out[b * NFC1 + o] = fmaxf(s + bias[o], 0.f);
}

// ============ tail [r7-verbatim] ============
__global__ __launch_bounds__(64) void tail_k(const float* __restrict__ fc1o,
        const float* __restrict__ fc2w, const float* __restrict__ fc2b,
        const float* __restrict__ centers,
        const float* __restrict__ w1, const float* __restrict__ b1,
        const float* __restrict__ w2, const float* __restrict__ b2,
        const float* __restrict__ w3, const float* __restrict__ b3,
        float* __restrict__ out) {
    const int b = blockIdx.x;
    const int lane = threadIdx.x;
    __shared__ float h[120];
    __shared__ float feat[4];
    __shared__ float bufA[64];
    __shared__ float bufB[64];

    for (int i = lane; i < NFC1; i += 64) h[i] = fc1o[b * NFC1 + i];
    __syncthreads();

    const int j = lane >> 4, p = lane & 15;
    float sv = 0.f;
    for (int o = p; o < NFC1; o += 16) sv = fmaf(fc2w[j * NFC1 + o], h[o], sv);
    #pragma unroll
    for (int off = 8; off; off >>= 1) sv += __shfl_xor(sv, off, 16);
    if (p == 0) feat[j] = fmaxf(sv + fc2b[j], 0.f);
    __syncthreads();

    float prod = 1.f;
    #pragma unroll
    for (int i = 0; i < 4; ++i) prod *= cosf(0.5f * (feat[i] - centers[lane * 84 + i]));
    bufA[lane] = fabsf(prod);
    __syncthreads();

    float s1 = b1[lane];
    for (int jj = 0; jj < 64; ++jj) s1 = fmaf(w1[lane * 64 + jj], bufA[jj], s1);
    bufB[lane] = fmaxf(s1, 0.f);
    __syncthreads();

    float s2 = b2[lane];
    for (int jj = 0; jj < 64; ++jj) s2 = fmaf(w2[lane * 64 + jj], bufB[jj], s2);
    bufA[lane] = fmaxf(s2, 0.f);
    __syncthreads();

    if (lane < 2) {
        float s3 = b3[lane];
        for (int jj = 0; jj < 64; ++jj) s3 = fmaf(w3[lane * 64 + jj], bufA[jj], s3);
        const float other = __shfl_xor(s3, 1, 2);
        const float m = fmaxf(s3, other);
        const float e = expf(s3 - m), eo = expf(other - m);
        out[b * 2 + lane] = e / (e + eo);
    }
}

// ---------------- launcher ----------------
extern "C" void kernel_launch(void* const* d_in, const int* in_sizes, int n_in,
                              void* d_out, int out_size, void* d_ws, size_t ws_size,
                              hipStream_t stream) {
    const float* x       = (const float*)d_in[0];
    const float* conv1_w = (const float*)d_in[1];
    const float* conv1_b = (const float*)d_in[2];
    const float* conv2_w = (const float*)d_in[3];
    const float* conv2_b = (const float*)d_in[4];
    const float* fc1_w   = (const float*)d_in[5];
    const float* fc1_b   = (const float*)d_in[6];
    const float* fc2_w   = (const float*)d_in[7];
    const float* fc2_b   = (const float*)d_in[8];
    const float* centers = (const float*)d_in[9];
    const float* cls_w1  = (const float*)d_in[10];
    const float* cls_b1  = (const float*)d_in[11];
    const float* cls_w2  = (const float*)d_in[12];
    const float* cls_b2  = (const float*)d_in[13];
    const float* cls_w3  = (const float*)d_in[14];
    const float* cls_b3  = (const float*)d_in[15];
    char* ws = (char*)d_ws;
    float* outp = (float*)d_out;

    float* p1    = (float*)(ws + oP1B);
    float* Abuf  = (float*)(ws + oAB);
    float* partb = (float*)(ws + oPARTB);
    float* fc1o  = (float*)(ws + oFC1B);

    hipLaunchKernelGGL(conv1_pool, dim3(18, 64), dim3(256), 0, stream, x, conv1_w, conv1_b, p1);
    hipLaunchKernelGGL(conv2_pool, dim3(5, 64), dim3(256), 0, stream, p1, conv2_w, conv2_b, Abuf);
    hipLaunchKernelGGL(fc1_s1, dim3(NCH), dim3(512), 0, stream, Abuf, fc1_w, partb);
    hipLaunchKernelGGL(fc1_s2, dim3(30), dim3(256), 0, stream, partb, fc1_b, fc1o);
    hipLaunchKernelGGL(tail_k, dim3(64), dim3(64), 0, stream,
                       fc1o, fc2_w, fc2_b, centers,
                       cls_w1, cls_b1, cls_w2, cls_b2, cls_w3, cls_b3, outp);
}

// Round 9
// 87.086 us; speedup vs baseline: 6.2225x; 1.5647x over previous
//
#include <hip/hip_runtime.h>
#include <hip/hip_bf16.h>

typedef float float4a __attribute__((ext_vector_type(4), aligned(4)));
typedef float float2a __attribute__((ext_vector_type(2), aligned(4)));
typedef short bfrag   __attribute__((ext_vector_type(8)));   // 8 bf16 (MFMA A/B frag)
typedef float f32x4   __attribute__((ext_vector_type(4)));

// ---------------- dims ----------------
#define P1W_PAD 128            // p1 row stride (f32), cols 123..127 zero
#define APAD 56064             // A row stride (f32) = 219*256, elems 55815.. zero
#define KFC 55815
#define CHUNK 256
#define NCHUNK 219
#define NFC1 120

// ws byte offsets
#define oP1B   ((size_t)0)            // 64*6*123*128*4 = 24,182,784
#define oAB    ((size_t)24182784)     // 64*56064*4     = 14,352,384
#define oPARTB ((size_t)38535168)     // 219*7680*4     =  6,727,680
#define oP2B   ((size_t)45262848)     // 8*7680*4       =    245,760

// ============ conv1 (3->6,k5,s2,p1)+ReLU+pool2s1 -> p1 f32[64][6][123][128] [r8-proven] ============
__global__ __launch_bounds__(256) void conv1_pool(const float* __restrict__ x,
        const float* __restrict__ w, const float* __restrict__ bias,
        float* __restrict__ p1) {
    __shared__ float ex[8 * 6 * 128];     // 24.6 KB
    const int tid = threadIdx.x;
    const int G = blockIdx.x;
    const int b = blockIdx.y;
    const int t = tid >> 5;
    const int s = tid & 31;
    const int r = 7 * G + t;
    const bool act = (r < 124) && (s < 31);

    if (act) {
        float acc[6][4];
        #pragma unroll
        for (int c = 0; c < 6; ++c) {
            const float bz = bias[c];
            #pragma unroll
            for (int j = 0; j < 4; ++j) acc[c][j] = bz;
        }
        for (int ic = 0; ic < 3; ++ic) {
            const float* xpl = x + (size_t)(b * 3 + ic) * 62500;
            #pragma unroll
            for (int ky = 0; ky < 5; ++ky) {
                const int iy = 2 * r - 1 + ky;
                if (iy < 0) continue;                       // top pad (bottom never hit)
                const float* rp = xpl + iy * 250 + 8 * s;
                float a[11];
                a[0] = (s > 0) ? rp[-1] : 0.f;              // left pad
                *(float4a*)&a[1] = *(const float4a*)rp;
                *(float4a*)&a[5] = *(const float4a*)(rp + 4);
                *(float2a*)&a[9] = *(const float2a*)(rp + 8);
                const float* wb = w + ic * 25 + ky * 5;     // + c*75 + kx (uniform s_loads)
                #pragma unroll
                for (int c = 0; c < 6; ++c) {
                    #pragma unroll
                    for (int kx = 0; kx < 5; ++kx) {
                        const float wv = wb[c * 75 + kx];
                        #pragma unroll
                        for (int j = 0; j < 4; ++j)
                            acc[c][j] = fmaf(a[2 * j + kx], wv, acc[c][j]);
                    }
                }
            }
        }
        #pragma unroll
        for (int c = 0; c < 6; ++c)
            *(float4*)&ex[(t * 6 + c) * 128 + 4 * s] = *(float4*)&acc[c][0];
    }
    __syncthreads();
    const int np = min(7, 123 - 7 * G);                     // pool rows this block
    for (int idx = tid; idx < np * 768; idx += 256) {       // 768 = 6*128
        const int p   = idx / 768;
        const int rem = idx - p * 768;                      // (768 != 2^n: no & trick)
        const int c   = rem >> 7;
        const int pc  = rem & 127;
        float v = 0.f;
        if (pc < 123) {
            const float* r0 = &ex[((p    ) * 6 + c) * 128 + pc];
            const float* r1 = &ex[((p + 1) * 6 + c) * 128 + pc];
            v = fmaxf(fmaxf(fmaxf(r0[0], r0[1]), fmaxf(r1[0], r1[1])), 0.f);
        }
        p1[((size_t)(b * 6 + c) * 123 + (7 * G + p)) * P1W_PAD + pc] = v;
    }
}

// ============ conv2 (6->15,k3,s2,p1)+ReLU+pool2s1 -> A f32[64][56064] [r8-proven] ============
__global__ __launch_bounds__(256) void conv2_pool(const float* __restrict__ p1,
        const float* __restrict__ w, const float* __restrict__ bias,
        float* __restrict__ A) {
    __shared__ float ex[16 * 15 * 64];    // 61.4 KB
    const int tid = threadIdx.x;
    const int G = blockIdx.x;
    const int b = blockIdx.y;
    const int t = tid >> 4;
    const int s = tid & 15;
    const int r = 15 * G + t;
    const bool act = (r < 62);

    if (act) {
        float acc[15][4];
        #pragma unroll
        for (int c = 0; c < 15; ++c) {
            const float bz = bias[c];
            #pragma unroll
            for (int j = 0; j < 4; ++j) acc[c][j] = bz;
        }
        for (int ic = 0; ic < 6; ++ic) {
            const float* pl = p1 + (size_t)(b * 6 + ic) * 123 * P1W_PAD;
            #pragma unroll
            for (int ky = 0; ky < 3; ++ky) {
                const int iy = 2 * r - 1 + ky;
                if (iy < 0 || iy > 122) continue;
                const float* rp = pl + iy * P1W_PAD + 8 * s;
                float a[9];
                a[0] = (s > 0) ? rp[-1] : 0.f;              // left pad (cols>=123 are 0)
                *(float4a*)&a[1] = *(const float4a*)rp;
                *(float4a*)&a[5] = *(const float4a*)(rp + 4);
                const float* wb = w + ic * 9 + ky * 3;      // + c*54 + kx (uniform)
                #pragma unroll
                for (int c = 0; c < 15; ++c) {
                    #pragma unroll
                    for (int kx = 0; kx < 3; ++kx) {
                        const float wv = wb[c * 54 + kx];
                        #pragma unroll
                        for (int j = 0; j < 4; ++j)
                            acc[c][j] = fmaf(a[2 * j + kx], wv, acc[c][j]);
                    }
                }
            }
        }
        #pragma unroll
        for (int c = 0; c < 15; ++c)
            *(float4*)&ex[(t * 15 + c) * 64 + 4 * s] = *(float4*)&acc[c][0];
    }
    __syncthreads();
    const int np = min(15, 61 - 15 * G);
    for (int idx = tid; idx < np * 915; idx += 256) {       // 915 = 15*61 (true modulo)
        const int p   = idx / 915;
        const int rem = idx % 915;
        const int c   = rem / 61;
        const int pc  = rem % 61;
        const float* r0 = &ex[((p    ) * 15 + c) * 64 + pc];
        const float* r1 = &ex[((p + 1) * 15 + c) * 64 + pc];
        const float v = fmaxf(fmaxf(r0[0], r0[1]), fmaxf(r1[0], r1[1]));
        A[(size_t)b * APAD + c * 3721 + (15 * G + p) * 61 + pc] = fmaxf(v, 0.f);
    }
    if (G == 0)                                             // zero the K-pad tail
        for (int i2 = tid; i2 < 249; i2 += 256)
            A[(size_t)b * APAD + KFC + i2] = 0.f;
}

// ============ fc1 split-K MFMA, split-precision bf16 (hi+lo), direct-global frags ============
// part[c][64 b][120 o]; grid 219 ; block 512 = 8 waves: mtile=wv&3, n-half=wv>>2
__global__ __launch_bounds__(512) void fc1_s1(const float* __restrict__ A,
        const float* __restrict__ W, float* __restrict__ part) {
    const int cBlk = blockIdx.x;
    const int k0 = cBlk * CHUNK;
    const int tid = threadIdx.x;
    const int lane  = tid & 63;
    const int wv    = tid >> 6;
    const int mtile = wv & 3;
    const int nth   = wv >> 2;            // 0/1 -> n-tiles 0..3 / 4..7
    const int ocol  = lane & 15;
    const int kq    = lane >> 4;          // 0..3 (k-quad within 32-wide MFMA K)
    const int arow  = mtile * 16 + ocol;

    // A fragments: direct global (16 rows x 32B per instr; kq groups complete each 128B line)
    bfrag ah[8], al[8];
    const float* abase = A + (size_t)arow * APAD + k0 + kq * 8;
    #pragma unroll
    for (int ks = 0; ks < 8; ++ks) {
        float af[8];
        *(float4a*)&af[0] = *(const float4a*)(abase + ks * 32);
        *(float4a*)&af[4] = *(const float4a*)(abase + ks * 32 + 4);
        #pragma unroll
        for (int e = 0; e < 8; ++e) {
            const unsigned u = __float_as_uint(af[e]);
            ah[ks][e] = (short)(u >> 16);                        // hi = trunc-bf16
            const float rres = af[e] - __uint_as_float(u & 0xffff0000u);  // exact
            al[ks][e] = (short)(__float_as_uint(rres) >> 16);    // lo = trunc-bf16(res)
        }
    }

    f32x4 acc[4];
    #pragma unroll
    for (int n = 0; n < 4; ++n) acc[n] = (f32x4){0.f, 0.f, 0.f, 0.f};

    #pragma unroll
    for (int ntl = 0; ntl < 4; ++ntl) {
        const int o  = (nth * 4 + ntl) * 16 + ocol;
        const int oc = min(o, NFC1 - 1);
        const float* wbase = W + (size_t)oc * KFC + k0 + kq * 8;
        #pragma unroll
        for (int ks = 0; ks < 8; ++ks) {
            float wf[8];
            if (cBlk != NCHUNK - 1) {
                *(float4a*)&wf[0] = *(const float4a*)(wbase + ks * 32);
                *(float4a*)&wf[4] = *(const float4a*)(wbase + ks * 32 + 4);
            } else {                                        // last chunk: guard OOB (W alloc end)
                const int kg = k0 + ks * 32 + kq * 8;
                #pragma unroll
                for (int e = 0; e < 8; ++e)
                    wf[e] = (kg + e < KFC) ? wbase[ks * 32 + e] : 0.f;
            }
            bfrag wh, wl;
            #pragma unroll
            for (int e = 0; e < 8; ++e) {
                const unsigned u = __float_as_uint(wf[e]);
                wh[e] = (short)(u >> 16);
                const float rres = wf[e] - __uint_as_float(u & 0xffff0000u);
                wl[e] = (short)(__float_as_uint(rres) >> 16);
            }
            acc[ntl] = __builtin_amdgcn_mfma_f32_16x16x32_bf16(ah[ks], wh, acc[ntl], 0, 0, 0);
            acc[ntl] = __builtin_amdgcn_mfma_f32_16x16x32_bf16(al[ks], wh, acc[ntl], 0, 0, 0);
            acc[ntl] = __builtin_amdgcn_mfma_f32_16x16x32_bf16(ah[ks], wl, acc[ntl], 0, 0, 0);
        }
    }
    #pragma unroll
    for (int ntl = 0; ntl < 4; ++ntl) {
        const int o = (nth * 4 + ntl) * 16 + ocol;
        if (o < NFC1) {
            #pragma unroll
            for (int rr = 0; rr < 4; ++rr) {
                const int brow = mtile * 16 + kq * 4 + rr;  // C/D: row=(l>>4)*4+reg, col=l&15
                part[((size_t)cBlk * 64 + brow) * NFC1 + o] = acc[ntl][rr];
            }
        }
    }
}

// ============ segment reduce: part2[8][7680] (219 = 3x28 + 5x27 chunks) ============
__global__ __launch_bounds__(256) void fc1_s2a(const float* __restrict__ part,
        float* __restrict__ part2) {
    const int idx = blockIdx.x * 256 + threadIdx.x;   // 61440
    const int seg = idx / 7680;
    const int r   = idx % 7680;
    const int c0 = seg * 27 + min(seg, 3);
    const int n  = 27 + (seg < 3 ? 1 : 0);
    float s = 0.f;
    for (int c = c0; c < c0 + n; ++c) s += part[(size_t)c * 7680 + r];
    part2[idx] = s;
}

// ============ tail: fc1 finish + fc2 rows 0..3 + fidelity + classifier + softmax ============
__global__ __launch_bounds__(64) void tail_k(const float* __restrict__ part2,
        const float* __restrict__ fc1b,
        const float* __restrict__ fc2w, const float* __restrict__ fc2b,
        const float* __restrict__ centers,
        const float* __restrict__ w1, const float* __restrict__ b1,
        const float* __restrict__ w2, const float* __restrict__ b2,
        const float* __restrict__ w3, const float* __restrict__ b3,
        float* __restrict__ out) {
    const int b = blockIdx.x;
    const int lane = threadIdx.x;
    __shared__ float h[120];
    __shared__ float feat[4];
    __shared__ float bufA[64];
    __shared__ float bufB[64];

    for (int o = lane; o < NFC1; o += 64) {
        float sv = fc1b[o];
        #pragma unroll
        for (int g = 0; g < 8; ++g) sv += part2[g * 7680 + b * NFC1 + o];
        h[o] = fmaxf(sv, 0.f);
    }
    __syncthreads();

    const int j = lane >> 4, p = lane & 15;
    float sv = 0.f;
    for (int o = p; o < NFC1; o += 16) sv = fmaf(fc2w[j * NFC1 + o], h[o], sv);
    #pragma unroll
    for (int off = 8; off; off >>= 1) sv += __shfl_xor(sv, off, 16);
    if (p == 0) feat[j] = fmaxf(sv + fc2b[j], 0.f);
    __syncthreads();

    float prod = 1.f;
    #pragma unroll
    for (int i = 0; i < 4; ++i) prod *= cosf(0.5f * (feat[i] - centers[lane * 84 + i]));
    bufA[lane] = fabsf(prod);
    __syncthreads();

    float s1 = b1[lane];
    for (int jj = 0; jj < 64; ++jj) s1 = fmaf(w1[lane * 64 + jj], bufA[jj], s1);
    bufB[lane] = fmaxf(s1, 0.f);
    __syncthreads();

    float s2 = b2[lane];
    for (int jj = 0; jj < 64; ++jj) s2 = fmaf(w2[lane * 64 + jj], bufB[jj], s2);
    bufA[lane] = fmaxf(s2, 0.f);
    __syncthreads();

    if (lane < 2) {
        float s3 = b3[lane];
        for (int jj = 0; jj < 64; ++jj) s3 = fmaf(w3[lane * 64 + jj], bufA[jj], s3);
        const float other = __shfl_xor(s3, 1, 2);
        const float m = fmaxf(s3, other);
        const float e = expf(s3 - m), eo = expf(other - m);
        out[b * 2 + lane] = e / (e + eo);
    }
}

// ---------------- launcher ----------------
extern "C" void kernel_launch(void* const* d_in, const int* in_sizes, int n_in,
                              void* d_out, int out_size, void* d_ws, size_t ws_size,
                              hipStream_t stream) {
    const float* x       = (const float*)d_in[0];
    const float* conv1_w = (const float*)d_in[1];
    const float* conv1_b = (const float*)d_in[2];
    const float* conv2_w = (const float*)d_in[3];
    const float* conv2_b = (const float*)d_in[4];
    const float* fc1_w   = (const float*)d_in[5];
    const float* fc1_b   = (const float*)d_in[6];
    const float* fc2_w   = (const float*)d_in[7];
    const float* fc2_b   = (const float*)d_in[8];
    const float* centers = (const float*)d_in[9];
    const float* cls_w1  = (const float*)d_in[10];
    const float* cls_b1  = (const float*)d_in[11];
    const float* cls_w2  = (const float*)d_in[12];
    const float* cls_b2  = (const float*)d_in[13];
    const float* cls_w3  = (const float*)d_in[14];
    const float* cls_b3  = (const float*)d_in[15];
    char* ws = (char*)d_ws;
    float* outp = (float*)d_out;

    float* p1    = (float*)(ws + oP1B);
    float* Abuf  = (float*)(ws + oAB);
    float* partb = (float*)(ws + oPARTB);
    float* part2 = (float*)(ws + oP2B);

    hipLaunchKernelGGL(conv1_pool, dim3(18, 64), dim3(256), 0, stream, x, conv1_w, conv1_b, p1);
    hipLaunchKernelGGL(conv2_pool, dim3(5, 64), dim3(256), 0, stream, p1, conv2_w, conv2_b, Abuf);
    hipLaunchKernelGGL(fc1_s1, dim3(NCHUNK), dim3(512), 0, stream, Abuf, fc1_w, partb);
    hipLaunchKernelGGL(fc1_s2a, dim3(240), dim3(256), 0, stream, partb, part2);
    hipLaunchKernelGGL(tail_k, dim3(64), dim3(64), 0, stream,
                       part2, fc1_b, fc2_w, fc2_b, centers,
                       cls_w1, cls_b1, cls_w2, cls_b2, cls_w3, cls_b3, outp);
}

// Round 10
// 86.004 us; speedup vs baseline: 6.3008x; 1.0126x over previous
//
#include <hip/hip_runtime.h>
#include <hip/hip_bf16.h>

typedef float float4a __attribute__((ext_vector_type(4), aligned(4)));
typedef float float2a __attribute__((ext_vector_type(2), aligned(4)));
typedef short bfrag   __attribute__((ext_vector_type(8)));   // 8 bf16 (MFMA A/B frag)
typedef float f32x4   __attribute__((ext_vector_type(4)));

// ---------------- dims ----------------
#define P1W_PAD 128            // p1 row stride (f32), cols 123..127 zero
#define APAD 56064             // A row stride (f32) = 219*256, elems 55815.. zero
#define KFC 55815
#define CHUNK 256
#define NCHUNK 219
#define NFC1 120

// ws byte offsets
#define oP1B   ((size_t)0)            // 64*6*123*128*4 = 24,182,784
#define oAB    ((size_t)24182784)     // 64*56064*4     = 14,352,384
#define oPARTB ((size_t)38535168)     // 219*7680*4     =  6,727,680
#define oP2B   ((size_t)45262848)     // 8*7680*4       =    245,760

// ============ conv1 (3->6,k5,s2,p1)+ReLU+pool2s1 -> p1 f32[64][6][123][128] [r8-proven] ============
__global__ __launch_bounds__(256) void conv1_pool(const float* __restrict__ x,
        const float* __restrict__ w, const float* __restrict__ bias,
        float* __restrict__ p1) {
    __shared__ float ex[8 * 6 * 128];     // 24.6 KB
    const int tid = threadIdx.x;
    const int G = blockIdx.x;
    const int b = blockIdx.y;
    const int t = tid >> 5;
    const int s = tid & 31;
    const int r = 7 * G + t;
    const bool act = (r < 124) && (s < 31);

    if (act) {
        float acc[6][4];
        #pragma unroll
        for (int c = 0; c < 6; ++c) {
            const float bz = bias[c];
            #pragma unroll
            for (int j = 0; j < 4; ++j) acc[c][j] = bz;
        }
        for (int ic = 0; ic < 3; ++ic) {
            const float* xpl = x + (size_t)(b * 3 + ic) * 62500;
            #pragma unroll
            for (int ky = 0; ky < 5; ++ky) {
                const int iy = 2 * r - 1 + ky;
                if (iy < 0) continue;                       // top pad (bottom never hit)
                const float* rp = xpl + iy * 250 + 8 * s;
                float a[11];
                a[0] = (s > 0) ? rp[-1] : 0.f;              // left pad
                *(float4a*)&a[1] = *(const float4a*)rp;
                *(float4a*)&a[5] = *(const float4a*)(rp + 4);
                *(float2a*)&a[9] = *(const float2a*)(rp + 8);
                const float* wb = w + ic * 25 + ky * 5;     // + c*75 + kx (uniform s_loads)
                #pragma unroll
                for (int c = 0; c < 6; ++c) {
                    #pragma unroll
                    for (int kx = 0; kx < 5; ++kx) {
                        const float wv = wb[c * 75 + kx];
                        #pragma unroll
                        for (int j = 0; j < 4; ++j)
                            acc[c][j] = fmaf(a[2 * j + kx], wv, acc[c][j]);
                    }
                }
            }
        }
        #pragma unroll
        for (int c = 0; c < 6; ++c)
            *(float4*)&ex[(t * 6 + c) * 128 + 4 * s] = *(float4*)&acc[c][0];
    }
    __syncthreads();
    const int np = min(7, 123 - 7 * G);                     // pool rows this block
    for (int idx = tid; idx < np * 768; idx += 256) {       // 768 = 6*128
        const int p   = idx / 768;
        const int rem = idx - p * 768;                      // (768 != 2^n: no & trick)
        const int c   = rem >> 7;
        const int pc  = rem & 127;
        float v = 0.f;
        if (pc < 123) {
            const float* r0 = &ex[((p    ) * 6 + c) * 128 + pc];
            const float* r1 = &ex[((p + 1) * 6 + c) * 128 + pc];
            v = fmaxf(fmaxf(fmaxf(r0[0], r0[1]), fmaxf(r1[0], r1[1])), 0.f);
        }
        p1[((size_t)(b * 6 + c) * 123 + (7 * G + p)) * P1W_PAD + pc] = v;
    }
}

// ============ conv2 (6->15,k3,s2,p1)+ReLU+pool2s1 -> A f32[64][56064] [r8-proven] ============
__global__ __launch_bounds__(256) void conv2_pool(const float* __restrict__ p1,
        const float* __restrict__ w, const float* __restrict__ bias,
        float* __restrict__ A) {
    __shared__ float ex[16 * 15 * 64];    // 61.4 KB
    const int tid = threadIdx.x;
    const int G = blockIdx.x;
    const int b = blockIdx.y;
    const int t = tid >> 4;
    const int s = tid & 15;
    const int r = 15 * G + t;
    const bool act = (r < 62);

    if (act) {
        float acc[15][4];
        #pragma unroll
        for (int c = 0; c < 15; ++c) {
            const float bz = bias[c];
            #pragma unroll
            for (int j = 0; j < 4; ++j) acc[c][j] = bz;
        }
        for (int ic = 0; ic < 6; ++ic) {
            const float* pl = p1 + (size_t)(b * 6 + ic) * 123 * P1W_PAD;
            #pragma unroll
            for (int ky = 0; ky < 3; ++ky) {
                const int iy = 2 * r - 1 + ky;
                if (iy < 0 || iy > 122) continue;
                const float* rp = pl + iy * P1W_PAD + 8 * s;
                float a[9];
                a[0] = (s > 0) ? rp[-1] : 0.f;              // left pad (cols>=123 are 0)
                *(float4a*)&a[1] = *(const float4a*)rp;
                *(float4a*)&a[5] = *(const float4a*)(rp + 4);
                const float* wb = w + ic * 9 + ky * 3;      // + c*54 + kx (uniform)
                #pragma unroll
                for (int c = 0; c < 15; ++c) {
                    #pragma unroll
                    for (int kx = 0; kx < 3; ++kx) {
                        const float wv = wb[c * 54 + kx];
                        #pragma unroll
                        for (int j = 0; j < 4; ++j)
                            acc[c][j] = fmaf(a[2 * j + kx], wv, acc[c][j]);
                    }
                }
            }
        }
        #pragma unroll
        for (int c = 0; c < 15; ++c)
            *(float4*)&ex[(t * 15 + c) * 64 + 4 * s] = *(float4*)&acc[c][0];
    }
    __syncthreads();
    const int np = min(15, 61 - 15 * G);
    for (int idx = tid; idx < np * 915; idx += 256) {       // 915 = 15*61 (true modulo)
        const int p   = idx / 915;
        const int rem = idx % 915;
        const int c   = rem / 61;
        const int pc  = rem % 61;
        const float* r0 = &ex[((p    ) * 15 + c) * 64 + pc];
        const float* r1 = &ex[((p + 1) * 15 + c) * 64 + pc];
        const float v = fmaxf(fmaxf(r0[0], r0[1]), fmaxf(r1[0], r1[1]));
        A[(size_t)b * APAD + c * 3721 + (15 * G + p) * 61 + pc] = fmaxf(v, 0.f);
    }
    if (G == 0)                                             // zero the K-pad tail
        for (int i2 = tid; i2 < 249; i2 += 256)
            A[(size_t)b * APAD + KFC + i2] = 0.f;
}

// ============ fc1 split-K MFMA v2: ks-outer, low VGPR, grid (219,2) ============
// part[c][64 b][120 o]; block 256 = 4 mtile waves; blockIdx.y = N-half (4 ntl = 64 outputs)
__global__ __launch_bounds__(256) void fc1_s1(const float* __restrict__ A,
        const float* __restrict__ W, float* __restrict__ part) {
    const int cBlk = blockIdx.x;
    const int nth  = blockIdx.y;          // 0/1
    const int k0 = cBlk * CHUNK;
    const int tid = threadIdx.x;
    const int lane  = tid & 63;
    const int mtile = tid >> 6;           // 0..3
    const int ocol  = lane & 15;
    const int kq    = lane >> 4;          // 0..3 (k-quad within 32-wide MFMA K)
    const int arow  = mtile * 16 + ocol;

    const float* ab = A + (size_t)arow * APAD + k0 + kq * 8;
    const float* wb[4];
    #pragma unroll
    for (int ntl = 0; ntl < 4; ++ntl) {
        const int o = (nth * 4 + ntl) * 16 + ocol;
        wb[ntl] = W + (size_t)min(o, NFC1 - 1) * KFC + k0 + kq * 8;
    }

    f32x4 acc[4];
    #pragma unroll
    for (int n = 0; n < 4; ++n) acc[n] = (f32x4){0.f, 0.f, 0.f, 0.f};

    const bool full = (cBlk != NCHUNK - 1);
    #pragma unroll 2
    for (int ks = 0; ks < 8; ++ks) {
        // A fragment for this ks only (8 VGPR live)
        float af[8];
        *(float4a*)&af[0] = *(const float4a*)(ab + ks * 32);
        *(float4a*)&af[4] = *(const float4a*)(ab + ks * 32 + 4);
        bfrag ah, al;
        #pragma unroll
        for (int e = 0; e < 8; ++e) {
            const unsigned u = __float_as_uint(af[e]);
            ah[e] = (short)(u >> 16);                            // hi = trunc-bf16
            const float rres = af[e] - __uint_as_float(u & 0xffff0000u);
            al[e] = (short)(__float_as_uint(rres) >> 16);        // lo = trunc-bf16(res)
        }
        #pragma unroll
        for (int ntl = 0; ntl < 4; ++ntl) {
            float wf[8];
            if (full) {
                *(float4a*)&wf[0] = *(const float4a*)(wb[ntl] + ks * 32);
                *(float4a*)&wf[4] = *(const float4a*)(wb[ntl] + ks * 32 + 4);
            } else {                                        // last chunk: guard OOB (W alloc end)
                const int kg = k0 + ks * 32 + kq * 8;
                #pragma unroll
                for (int e = 0; e < 8; ++e)
                    wf[e] = (kg + e < KFC) ? wb[ntl][ks * 32 + e] : 0.f;
            }
            bfrag wh, wl;
            #pragma unroll
            for (int e = 0; e < 8; ++e) {
                const unsigned u = __float_as_uint(wf[e]);
                wh[e] = (short)(u >> 16);
                const float rres = wf[e] - __uint_as_float(u & 0xffff0000u);
                wl[e] = (short)(__float_as_uint(rres) >> 16);
            }
            acc[ntl] = __builtin_amdgcn_mfma_f32_16x16x32_bf16(ah, wh, acc[ntl], 0, 0, 0);
            acc[ntl] = __builtin_amdgcn_mfma_f32_16x16x32_bf16(al, wh, acc[ntl], 0, 0, 0);
            acc[ntl] = __builtin_amdgcn_mfma_f32_16x16x32_bf16(ah, wl, acc[ntl], 0, 0, 0);
        }
    }
    #pragma unroll
    for (int ntl = 0; ntl < 4; ++ntl) {
        const int o = (nth * 4 + ntl) * 16 + ocol;
        if (o < NFC1) {
            #pragma unroll
            for (int rr = 0; rr < 4; ++rr) {
                const int brow = mtile * 16 + kq * 4 + rr;  // C/D: row=(l>>4)*4+reg, col=l&15
                part[((size_t)cBlk * 64 + brow) * NFC1 + o] = acc[ntl][rr];
            }
        }
    }
}

// ============ segment reduce: part2[8][7680] (219 = 3x28 + 5x27 chunks) ============
__global__ __launch_bounds__(256) void fc1_s2a(const float* __restrict__ part,
        float* __restrict__ part2) {
    const int idx = blockIdx.x * 256 + threadIdx.x;   // 61440
    const int seg = idx / 7680;
    const int r   = idx % 7680;
    const int c0 = seg * 27 + min(seg, 3);
    const int n  = 27 + (seg < 3 ? 1 : 0);
    float s = 0.f;
    for (int c = c0; c < c0 + n; ++c) s += part[(size_t)c * 7680 + r];
    part2[idx] = s;
}

// ============ tail: fc1 finish + fc2 rows 0..3 + fidelity + classifier + softmax ============
__global__ __launch_bounds__(64) void tail_k(const float* __restrict__ part2,
        const float* __restrict__ fc1b,
        const float* __restrict__ fc2w, const float* __restrict__ fc2b,
        const float* __restrict__ centers,
        const float* __restrict__ w1, const float* __restrict__ b1,
        const float* __restrict__ w2, const float* __restrict__ b2,
        const float* __restrict__ w3, const float* __restrict__ b3,
        float* __restrict__ out) {
    const int b = blockIdx.x;
    const int lane = threadIdx.x;
    __shared__ float h[120];
    __shared__ float feat[4];
    __shared__ float bufA[64];
    __shared__ float bufB[64];

    for (int o = lane; o < NFC1; o += 64) {
        float sv = fc1b[o];
        #pragma unroll
        for (int g = 0; g < 8; ++g) sv += part2[g * 7680 + b * NFC1 + o];
        h[o] = fmaxf(sv, 0.f);
    }
    __syncthreads();

    const int j = lane >> 4, p = lane & 15;
    float sv = 0.f;
    for (int o = p; o < NFC1; o += 16) sv = fmaf(fc2w[j * NFC1 + o], h[o], sv);
    #pragma unroll
    for (int off = 8; off; off >>= 1) sv += __shfl_xor(sv, off, 16);
    if (p == 0) feat[j] = fmaxf(sv + fc2b[j], 0.f);
    __syncthreads();

    float prod = 1.f;
    #pragma unroll
    for (int i = 0; i < 4; ++i) prod *= cosf(0.5f * (feat[i] - centers[lane * 84 + i]));
    bufA[lane] = fabsf(prod);
    __syncthreads();

    float s1 = b1[lane];
    for (int jj = 0; jj < 64; ++jj) s1 = fmaf(w1[lane * 64 + jj], bufA[jj], s1);
    bufB[lane] = fmaxf(s1, 0.f);
    __syncthreads();

    float s2 = b2[lane];
    for (int jj = 0; jj < 64; ++jj) s2 = fmaf(w2[lane * 64 + jj], bufB[jj], s2);
    bufA[lane] = fmaxf(s2, 0.f);
    __syncthreads();

    if (lane < 2) {
        float s3 = b3[lane];
        for (int jj = 0; jj < 64; ++jj) s3 = fmaf(w3[lane * 64 + jj], bufA[jj], s3);
        const float other = __shfl_xor(s3, 1, 2);
        const float m = fmaxf(s3, other);
        const float e = expf(s3 - m), eo = expf(other - m);
        out[b * 2 + lane] = e / (e + eo);
    }
}

// ---------------- launcher ----------------
extern "C" void kernel_launch(void* const* d_in, const int* in_sizes, int n_in,
                              void* d_out, int out_size, void* d_ws, size_t ws_size,
                              hipStream_t stream) {
    const float* x       = (const float*)d_in[0];
    const float* conv1_w = (const float*)d_in[1];
    const float* conv1_b = (const float*)d_in[2];
    const float* conv2_w = (const float*)d_in[3];
    const float* conv2_b = (const float*)d_in[4];
    const float* fc1_w   = (const float*)d_in[5];
    const float* fc1_b   = (const float*)d_in[6];
    const float* fc2_w   = (const float*)d_in[7];
    const float* fc2_b   = (const float*)d_in[8];
    const float* centers = (const float*)d_in[9];
    const float* cls_w1  = (const float*)d_in[10];
    const float* cls_b1  = (const float*)d_in[11];
    const float* cls_w2  = (const float*)d_in[12];
    const float* cls_b2  = (const float*)d_in[13];
    const float* cls_w3  = (const float*)d_in[14];
    const float* cls_b3  = (const float*)d_in[15];
    char* ws = (char*)d_ws;
    float* outp = (float*)d_out;

    float* p1    = (float*)(ws + oP1B);
    float* Abuf  = (float*)(ws + oAB);
    float* partb = (float*)(ws + oPARTB);
    float* part2 = (float*)(ws + oP2B);

    hipLaunchKernelGGL(conv1_pool, dim3(18, 64), dim3(256), 0, stream, x, conv1_w, conv1_b, p1);
    hipLaunchKernelGGL(conv2_pool, dim3(5, 64), dim3(256), 0, stream, p1, conv2_w, conv2_b, Abuf);
    hipLaunchKernelGGL(fc1_s1, dim3(NCHUNK, 2), dim3(256), 0, stream, Abuf, fc1_w, partb);
    hipLaunchKernelGGL(fc1_s2a, dim3(240), dim3(256), 0, stream, partb, part2);
    hipLaunchKernelGGL(tail_k, dim3(64), dim3(64), 0, stream,
                       part2, fc1_b, fc2_w, fc2_b, centers,
                       cls_w1, cls_b1, cls_w2, cls_b2, cls_w3, cls_b3, outp);
}